// Round 6
// baseline (104.841 us; speedup 1.0000x reference)
//
#include <hip/hip_runtime.h>

// Chamfer distance: B=4, N=M=8192, D=3, fp32. VALU issue-bound.
// Symmetric kernel: each pair computed ONCE (3 FMA + row-min3 + col add/min3
// ~= 5.25 issues/pair). j-fast geometry: row reduce = intra-wave butterfly
// (no barriers in main loop); col reduce = reg accs + LDS atomicMin at end.
// mlds XOR-swizzled (4-way max on ds_read_b128).

#define B_ 4
#define N_ 8192
#define TM 1024
#define SM (N_ / TM)     // 8 row-partial splits
#define THREADS 512
#define INF32 3.4e38f

__device__ __forceinline__ float min3f(float a, float b, float c) {
  float d;
  asm("v_min3_f32 %0, %1, %2, %3" : "=v"(d) : "v"(a), "v"(b), "v"(c));
  return d;
}

// grid (SM, SN, B_); SN = N_/(RC*64). 512 threads = 32 j (lane-fast) x 16 iq.
__global__ __launch_bounds__(THREADS, 4) void chamfer_sym(
    const float* __restrict__ pred, const float* __restrict__ gt,
    float* __restrict__ rowpart, unsigned* __restrict__ colpart,
    float* __restrict__ accws, int RC) {
  __shared__ float4 mlds[TM];        // 16 KB, XOR-swizzled packed (x,y,z,|t|^2)
  __shared__ unsigned colbuf[TM];    // 4 KB, col-min bits (clamped >=0)

  const int b = blockIdx.z, tn = blockIdx.y, tm = blockIdx.x;
  const int tid = threadIdx.x;
  const int j = tid & 31;            // intra-wave col-group index
  const int iq = tid >> 5;           // row-group index (0..15)
  const int SN = gridDim.y;
  const int TN = N_ / SN;            // RC*64 rows per block

  if (b == 0 && tn == 0 && tm == 0 && tid == 0) {
    accws[0] = 0.0f;
    ((unsigned*)accws)[1] = 0u;
  }

  const float* qsrc = pred + (size_t)b * N_ * 3;   // rows = pred
  const float* tsrc = gt + (size_t)b * N_ * 3;     // cols = gt

  // ---- stage m-tile packed+swizzled; init colbuf ----
  if (tid < 256) {
    const float* tb = tsrc + (size_t)tm * TM * 3 + tid * 12;
    const float4 f0 = *(const float4*)(tb);
    const float4 f1 = *(const float4*)(tb + 4);
    const float4 f2 = *(const float4*)(tb + 8);
    float4 P0 = make_float4(f0.x, f0.y, f0.z, fmaf(f0.x,f0.x, fmaf(f0.y,f0.y, f0.z*f0.z)));
    float4 P1 = make_float4(f0.w, f1.x, f1.y, fmaf(f0.w,f0.w, fmaf(f1.x,f1.x, f1.y*f1.y)));
    float4 P2 = make_float4(f1.z, f1.w, f2.x, fmaf(f1.z,f1.z, fmaf(f1.w,f1.w, f2.x*f2.x)));
    float4 P3 = make_float4(f2.y, f2.z, f2.w, fmaf(f2.y,f2.y, fmaf(f2.z,f2.z, f2.w*f2.w)));
    const int s = (tid >> 3) & 3;    // = ((4*tid)>>5)&3
    const int base = tid * 4;
    mlds[base + (0 ^ s)] = P0;
    mlds[base + (1 ^ s)] = P1;
    mlds[base + (2 ^ s)] = P2;
    mlds[base + (3 ^ s)] = P3;
    ((uint4*)colbuf)[tid] = make_uint4(0x7F7FFFFFu, 0x7F7FFFFFu, 0x7F7FFFFFu, 0x7F7FFFFFu);
  }

  float colacc[32];
#pragma unroll
  for (int c = 0; c < 32; ++c) colacc[c] = INF32;

  __syncthreads();

  // swizzled read slots for this thread's 4 cols (cs folds into imm offset)
  const int sw = (j >> 3) & 3;
  const int a0 = 4 * j + (0 ^ sw);
  const int a1 = 4 * j + (1 ^ sw);
  const int a2 = 4 * j + (2 ^ sw);
  const int a3 = 4 * j + (3 ^ sw);

  for (int rc = 0; rc < RC; ++rc) {
    const int r0 = tn * TN + rc * 64 + iq * 4;     // this thread's 4 rows
    const float* qb = qsrc + (size_t)r0 * 3;       // 48B-aligned
    const float4 g0 = *(const float4*)(qb);
    const float4 g1 = *(const float4*)(qb + 4);
    const float4 g2 = *(const float4*)(qb + 8);
    const float qx[4] = {g0.x, g0.w, g1.z, g2.y};
    const float qy[4] = {g0.y, g1.x, g1.w, g2.z};
    const float qz[4] = {g0.z, g1.y, g2.x, g2.w};
    float nx[4], ny[4], nz[4], q2[4], racc[4];
#pragma unroll
    for (int r = 0; r < 4; ++r) {
      nx[r] = -2.0f * qx[r]; ny[r] = -2.0f * qy[r]; nz[r] = -2.0f * qz[r];
      q2[r] = fmaf(qx[r], qx[r], fmaf(qy[r], qy[r], qz[r] * qz[r]));
      racc[r] = INF32;
    }

#pragma unroll
    for (int cs = 0; cs < 8; ++cs) {
      const float4 t0 = mlds[cs * 128 + a0];
      const float4 t1 = mlds[cs * 128 + a1];
      const float4 t2 = mlds[cs * 128 + a2];
      const float4 t3 = mlds[cs * 128 + a3];
      float sc[4][4];
#pragma unroll
      for (int r = 0; r < 4; ++r) {
        sc[r][0] = fmaf(nx[r], t0.x, fmaf(ny[r], t0.y, fmaf(nz[r], t0.z, t0.w)));
        sc[r][1] = fmaf(nx[r], t1.x, fmaf(ny[r], t1.y, fmaf(nz[r], t1.z, t1.w)));
        sc[r][2] = fmaf(nx[r], t2.x, fmaf(ny[r], t2.y, fmaf(nz[r], t2.z, t2.w)));
        sc[r][3] = fmaf(nx[r], t3.x, fmaf(ny[r], t3.y, fmaf(nz[r], t3.z, t3.w)));
        racc[r] = min3f(racc[r], sc[r][0], sc[r][1]);
        racc[r] = min3f(racc[r], sc[r][2], sc[r][3]);
      }
#pragma unroll
      for (int c = 0; c < 4; ++c) {
        colacc[cs*4+c] = min3f(colacc[cs*4+c], sc[0][c] + q2[0], sc[1][c] + q2[1]);
        colacc[cs*4+c] = min3f(colacc[cs*4+c], sc[2][c] + q2[2], sc[3][c] + q2[3]);
      }
    }

    // row-min across the 32 j-lanes (intra-wave butterfly, no barrier)
#pragma unroll
    for (int m = 1; m <= 16; m <<= 1) {
#pragma unroll
      for (int r = 0; r < 4; ++r)
        racc[r] = fminf(racc[r], __shfl_xor(racc[r], m, 64));
    }
    if (j == 0) {
      float4 v = make_float4(racc[0] + q2[0], racc[1] + q2[1],
                             racc[2] + q2[2], racc[3] + q2[3]);
      *(float4*)&rowpart[((size_t)b * SM + tm) * N_ + r0] = v;
    }
  }

  // col-min: pair-reduce across iq halves, then LDS atomicMin
#pragma unroll
  for (int c = 0; c < 32; ++c)
    colacc[c] = fminf(colacc[c], __shfl_xor(colacc[c], 32, 64));
  if ((tid & 32) == 0) {
#pragma unroll
    for (int cs = 0; cs < 8; ++cs)
#pragma unroll
      for (int c = 0; c < 4; ++c)
        atomicMin(&colbuf[cs * 128 + 4 * j + c],
                  __float_as_uint(fmaxf(colacc[cs*4+c], 0.0f)));
  }
  __syncthreads();
  {
    unsigned* dst = colpart + ((size_t)b * SN + tn) * N_ + tm * TM;
    dst[tid] = colbuf[tid];
    dst[tid + 512] = colbuf[tid + 512];
  }
}

__global__ __launch_bounds__(256) void chamfer_fin(
    const float* __restrict__ rowpart, const unsigned* __restrict__ colpart,
    float* __restrict__ accws, float* __restrict__ out, int SN) {
  const int t = blockIdx.x * 256 + threadIdx.x;    // 0..65535
  float v;
  if (t < 32768) {
    const int b = t >> 13, n = t & (N_ - 1);
    const float* p = rowpart + (size_t)b * SM * N_ + n;
    v = p[0];
#pragma unroll
    for (int s2 = 1; s2 < SM; ++s2) v = fminf(v, p[(size_t)s2 * N_]);
  } else {
    const int u = t - 32768;
    const int b = u >> 13, n = u & (N_ - 1);
    const unsigned* p = colpart + (size_t)b * SN * N_ + n;
    unsigned m = p[0];
    for (int s2 = 1; s2 < SN; ++s2) m = min(m, p[(size_t)s2 * N_]);
    v = __uint_as_float(m);
  }
  float sum = sqrtf(fmaxf(v, 0.0f));
#pragma unroll
  for (int off = 32; off > 0; off >>= 1) sum += __shfl_down(sum, off, 64);
  __shared__ float ws4[4];
  const int lane = threadIdx.x & 63, wid = threadIdx.x >> 6;
  if (lane == 0) ws4[wid] = sum;
  __syncthreads();
  if (threadIdx.x == 0) {
    const float bs = (ws4[0] + ws4[1]) + (ws4[2] + ws4[3]);
    atomicAdd(&accws[0], bs);
    __threadfence();
    const unsigned old = atomicAdd(((unsigned*)accws) + 1, 1u);
    if (old == gridDim.x - 1) {
      __threadfence();
      const float tot = atomicAdd(&accws[0], 0.0f);
      out[0] = tot * (1.0f / 32768.0f);   // /(B*N) per direction, N==M
    }
  }
}

extern "C" void kernel_launch(void* const* d_in, const int* in_sizes, int n_in,
                              void* d_out, int out_size, void* d_ws, size_t ws_size,
                              hipStream_t stream) {
  const float* pred = (const float*)d_in[0];  // [B, N, 3]
  const float* gt   = (const float*)d_in[1];  // [B, M, 3]
  float* out = (float*)d_out;

  float* accws = (float*)d_ws;                           // 2 words
  float* rowpart = (float*)((char*)d_ws + 64);           // B*SM*N floats = 1 MB
  unsigned* colpart = (unsigned*)(rowpart + (size_t)B_ * SM * N_);

  const size_t base = 64 + (size_t)B_ * SM * N_ * 4;
  int RC = 16;                                           // SN=8, colpart 1 MB
  if (ws_size >= base + (size_t)B_ * 32 * N_ * 4) RC = 4;       // SN=32, 4 MB
  else if (ws_size >= base + (size_t)B_ * 16 * N_ * 4) RC = 8;  // SN=16, 2 MB
  const int SN = N_ / (RC * 64);

  chamfer_sym<<<dim3(SM, SN, B_), THREADS, 0, stream>>>(
      pred, gt, rowpart, colpart, accws, RC);
  chamfer_fin<<<256, 256, 0, stream>>>(rowpart, colpart, accws, out, SN);
}

// Round 7
// 101.509 us; speedup vs baseline: 1.0328x; 1.0328x over previous
//
#include <hip/hip_runtime.h>

// Chamfer distance: B=4, N=M=8192, D=3, fp32. VALU issue-bound.
// Symmetric tile kernel: each pair computed ONCE via packed-fp32 VOP3P
// (v_pk_fma_f32 with op_sel scalar broadcast): 3.0 VALU issues/pair.
// 8 rows/thread halves LDS traffic; LDS stride padded to 5 float4s.
// Results land via global atomicMin (fp bits, clamped >=0) -> trivial fin.

#define B_ 4
#define N_ 8192
#define TM 1024
#define SM 8           // col tiles (N_/TM)
#define SN 16          // row tiles
#define TN 512         // rows per block (N_/SN)
#define THREADS 512    // 32 j (cols) x 16 iq (rows)

typedef float f32x2 __attribute__((ext_vector_type(2)));
typedef float f32x4 __attribute__((ext_vector_type(4)));

__device__ __forceinline__ float min3f(float a, float b, float c) {
  float d;
  asm("v_min3_f32 %0, %1, %2, %3" : "=v"(d) : "v"(a), "v"(b), "v"(c));
  return d;
}
__device__ __forceinline__ f32x2 mk2(float a, float b) { f32x2 r; r.x = a; r.y = b; return r; }

// pk fma with src0 broadcast from lo/hi half of its register pair.
__device__ __forceinline__ f32x2 pk_fma_blo(f32x2 bc, f32x2 b, f32x2 c) {
  f32x2 d;
  asm("v_pk_fma_f32 %0, %1, %2, %3 op_sel:[0,0,0] op_sel_hi:[0,1,1]"
      : "=v"(d) : "v"(bc), "v"(b), "v"(c));
  return d;
}
__device__ __forceinline__ f32x2 pk_fma_bhi(f32x2 bc, f32x2 b, f32x2 c) {
  f32x2 d;
  asm("v_pk_fma_f32 %0, %1, %2, %3 op_sel:[1,0,0] op_sel_hi:[1,1,1]"
      : "=v"(d) : "v"(bc), "v"(b), "v"(c));
  return d;
}
// pk add with src1 broadcast from lo/hi half.
__device__ __forceinline__ f32x2 pk_add_blo(f32x2 a, f32x2 bc) {
  f32x2 d;
  asm("v_pk_add_f32 %0, %1, %2 op_sel:[0,0] op_sel_hi:[1,0]"
      : "=v"(d) : "v"(a), "v"(bc));
  return d;
}
__device__ __forceinline__ f32x2 pk_add_bhi(f32x2 a, f32x2 bc) {
  f32x2 d;
  asm("v_pk_add_f32 %0, %1, %2 op_sel:[0,1] op_sel_hi:[1,1]"
      : "=v"(d) : "v"(a), "v"(bc));
  return d;
}

// grid (SM, SN, B_), 512 threads. Targets (gt) tiled in LDS pair-packed:
// pair k -> A=(x0,x1,y0,y1), B=(z0,z1,w0,w1); 5-float4 stride per j-slot.
__global__ __launch_bounds__(THREADS, 2) void chamfer_sym(
    const float* __restrict__ pred, const float* __restrict__ gt,
    unsigned* __restrict__ rowmin, unsigned* __restrict__ colmin,
    float* __restrict__ accws) {
  __shared__ f32x4 mlds[8 * 160];      // 20 KB (8 strips x 32 j x 5 entries)
  __shared__ unsigned colbuf[TM];      // 4 KB

  const int bb = blockIdx.z, tn = blockIdx.y, tm = blockIdx.x;
  const int tid = threadIdx.x;
  const int j = tid & 31;
  const int iq = tid >> 5;

  if (bb == 0 && tn == 0 && tm == 0 && tid < 2)
    ((unsigned*)accws)[tid] = 0u;      // zero sum + counter for fin

  const float* qsrc = pred + (size_t)bb * N_ * 3;   // rows = pred
  const float* tsrc = gt + (size_t)bb * N_ * 3;     // cols = gt

  // ---- stage 1024 targets, pair-packed, padded stride ----
  if (tid < 256) {
    const float* tb = tsrc + (size_t)tm * TM * 3 + tid * 12;
    const f32x4 f0 = *(const f32x4*)(tb);
    const f32x4 f1 = *(const f32x4*)(tb + 4);
    const f32x4 f2 = *(const f32x4*)(tb + 8);
    // points p0..p3
    const float x0 = f0.x, y0 = f0.y, z0 = f0.z;
    const float x1 = f0.w, y1 = f1.x, z1 = f1.y;
    const float x2 = f1.z, y2 = f1.w, z2 = f2.x;
    const float x3 = f2.y, y3 = f2.z, z3 = f2.w;
    const float w0 = fmaf(x0, x0, fmaf(y0, y0, z0 * z0));
    const float w1 = fmaf(x1, x1, fmaf(y1, y1, z1 * z1));
    const float w2 = fmaf(x2, x2, fmaf(y2, y2, z2 * z2));
    const float w3 = fmaf(x3, x3, fmaf(y3, y3, z3 * z3));
    const int base = (tid >> 5) * 160 + 5 * (tid & 31);
    f32x4 A0; A0.x = x0; A0.y = x1; A0.z = y0; A0.w = y1;
    f32x4 B0; B0.x = z0; B0.y = z1; B0.z = w0; B0.w = w1;
    f32x4 A1; A1.x = x2; A1.y = x3; A1.z = y2; A1.w = y3;
    f32x4 B1; B1.x = z2; B1.y = z3; B1.z = w2; B1.w = w3;
    mlds[base + 0] = A0; mlds[base + 1] = B0;
    mlds[base + 2] = A1; mlds[base + 3] = B1;
    uint4 inf4; inf4.x = inf4.y = inf4.z = inf4.w = 0xFFFFFFFFu;
    ((uint4*)colbuf)[tid] = inf4;
  }

  float colacc[32];
#pragma unroll
  for (int c = 0; c < 32; ++c) colacc[c] = 3.4e38f;

  __syncthreads();

// one row's 3 pk_fma + row-min + col d2 (SEL broadcasts lo/hi of pair RR)
#define ROW(r, RR, SEL)                                                \
  f32x2 d##r;                                                          \
  {                                                                    \
    f32x2 s = pk_fma_##SEL(nzp[RR], zz, ww);                           \
    s = pk_fma_##SEL(nyp[RR], yy, s);                                  \
    s = pk_fma_##SEL(nxp[RR], xx, s);                                  \
    racc[r] = min3f(racc[r], s.x, s.y);                                \
    d##r = pk_add_##SEL(s, q2p[RR]);                                   \
  }

#define PAIR(CIDX)                                                     \
  {                                                                    \
    ROW(0, 0, blo) ROW(1, 0, bhi) ROW(2, 1, blo) ROW(3, 1, bhi)        \
    ROW(4, 2, blo) ROW(5, 2, bhi) ROW(6, 3, blo) ROW(7, 3, bhi)        \
    colacc[CIDX] = min3f(colacc[CIDX], min3f(d0.x, d1.x, d2.x),        \
                         min3f(d3.x, d4.x, d5.x));                     \
    colacc[CIDX] = min3f(colacc[CIDX], d6.x, d7.x);                    \
    colacc[CIDX + 1] = min3f(colacc[CIDX + 1], min3f(d0.y, d1.y, d2.y),\
                             min3f(d3.y, d4.y, d5.y));                 \
    colacc[CIDX + 1] = min3f(colacc[CIDX + 1], d6.y, d7.y);            \
  }

  for (int rc = 0; rc < 4; ++rc) {
    const int r0 = tn * TN + rc * 128 + iq * 8;     // this thread's 8 rows
    const float* qb = qsrc + (size_t)r0 * 3;        // 16B-aligned (r0 % 8 == 0)
    const f32x4 a0 = *(const f32x4*)(qb);
    const f32x4 a1 = *(const f32x4*)(qb + 4);
    const f32x4 a2 = *(const f32x4*)(qb + 8);
    const f32x4 a3 = *(const f32x4*)(qb + 12);
    const f32x4 a4 = *(const f32x4*)(qb + 16);
    const f32x4 a5 = *(const f32x4*)(qb + 20);
    const float px[8] = {a0.x, a0.w, a1.z, a2.y, a3.x, a3.w, a4.z, a5.y};
    const float py[8] = {a0.y, a1.x, a1.w, a2.z, a3.y, a4.x, a4.w, a5.z};
    const float pz[8] = {a0.z, a1.y, a2.x, a2.w, a3.z, a4.y, a5.x, a5.w};
    f32x2 nxp[4], nyp[4], nzp[4], q2p[4];
#pragma unroll
    for (int k = 0; k < 4; ++k) {
      nxp[k] = mk2(-2.f * px[2 * k], -2.f * px[2 * k + 1]);
      nyp[k] = mk2(-2.f * py[2 * k], -2.f * py[2 * k + 1]);
      nzp[k] = mk2(-2.f * pz[2 * k], -2.f * pz[2 * k + 1]);
      q2p[k] = mk2(
          fmaf(px[2*k], px[2*k], fmaf(py[2*k], py[2*k], pz[2*k] * pz[2*k])),
          fmaf(px[2*k+1], px[2*k+1],
               fmaf(py[2*k+1], py[2*k+1], pz[2*k+1] * pz[2*k+1])));
    }

    float racc[8];
#pragma unroll
    for (int r = 0; r < 8; ++r) racc[r] = 3.4e38f;

#pragma unroll
    for (int cs = 0; cs < 8; ++cs) {
      const int base = cs * 160 + 5 * j;
      const f32x4 e0 = mlds[base + 0];
      const f32x4 e1 = mlds[base + 1];
      const f32x4 e2 = mlds[base + 2];
      const f32x4 e3 = mlds[base + 3];
      {
        const f32x2 xx = e0.xy, yy = e0.zw, zz = e1.xy, ww = e1.zw;
        PAIR(cs * 4)
      }
      {
        const f32x2 xx = e2.xy, yy = e2.zw, zz = e3.xy, ww = e3.zw;
        PAIR(cs * 4 + 2)
      }
    }

    // row-min across 32 j-lanes (intra-half butterfly, no barrier)
#pragma unroll
    for (int m = 1; m <= 16; m <<= 1)
#pragma unroll
      for (int r = 0; r < 8; ++r)
        racc[r] = fminf(racc[r], __shfl_xor(racc[r], m, 64));
    if (j == 0) {
      unsigned* rp = rowmin + (size_t)bb * N_ + r0;
#pragma unroll
      for (int r = 0; r < 8; ++r) {
        const float q2s = (r & 1) ? q2p[r >> 1].y : q2p[r >> 1].x;
        atomicMin(&rp[r], __float_as_uint(fmaxf(racc[r] + q2s, 0.f)));
      }
    }
  }

  // ---- col mins: pair-reduce across iq halves, LDS atomicMin, flush ----
#pragma unroll
  for (int c = 0; c < 32; ++c)
    colacc[c] = fminf(colacc[c], __shfl_xor(colacc[c], 32, 64));
  if ((tid & 32) == 0) {
#pragma unroll
    for (int cs = 0; cs < 8; ++cs)
#pragma unroll
      for (int k = 0; k < 4; ++k)
        atomicMin(&colbuf[cs * 128 + 4 * j + k],
                  __float_as_uint(fmaxf(colacc[cs * 4 + k], 0.f)));
  }
  __syncthreads();
  {
    unsigned* cp = colmin + (size_t)bb * N_ + tm * TM;
    atomicMin(&cp[tid], colbuf[tid]);
    atomicMin(&cp[tid + 512], colbuf[tid + 512]);
  }
#undef ROW
#undef PAIR
}

// minbuf = rowmin ++ colmin, 65536 uints (fp bits, all >= 0). 64 blocks x 256.
__global__ __launch_bounds__(256) void chamfer_fin(
    const unsigned* __restrict__ minbuf, float* __restrict__ accws,
    float* __restrict__ out) {
  const int t = blockIdx.x * 256 + threadIdx.x;
  const uint4 v = ((const uint4*)minbuf)[t];
  float sum = sqrtf(__uint_as_float(v.x)) + sqrtf(__uint_as_float(v.y)) +
              sqrtf(__uint_as_float(v.z)) + sqrtf(__uint_as_float(v.w));
#pragma unroll
  for (int off = 32; off > 0; off >>= 1) sum += __shfl_down(sum, off, 64);
  __shared__ float ws4[4];
  const int lane = threadIdx.x & 63, wid = threadIdx.x >> 6;
  if (lane == 0) ws4[wid] = sum;
  __syncthreads();
  if (threadIdx.x == 0) {
    const float bs = (ws4[0] + ws4[1]) + (ws4[2] + ws4[3]);
    atomicAdd(&accws[0], bs);
    __threadfence();
    const unsigned old = atomicAdd(((unsigned*)accws) + 1, 1u);
    if (old == gridDim.x - 1) {
      __threadfence();
      const float tot = atomicAdd(&accws[0], 0.0f);
      out[0] = tot * (1.0f / 32768.0f);   // /(B*N) per direction, N==M
    }
  }
}

extern "C" void kernel_launch(void* const* d_in, const int* in_sizes, int n_in,
                              void* d_out, int out_size, void* d_ws, size_t ws_size,
                              hipStream_t stream) {
  const float* pred = (const float*)d_in[0];  // [B, N, 3]
  const float* gt   = (const float*)d_in[1];  // [B, M, 3]
  float* out = (float*)d_out;

  float* accws = (float*)d_ws;                              // 2 words
  unsigned* rowmin = (unsigned*)((char*)d_ws + 64);         // B*N uints
  unsigned* colmin = rowmin + (size_t)B_ * N_;              // B*M uints

  hipMemsetAsync(rowmin, 0xFF, (size_t)2 * B_ * N_ * sizeof(unsigned), stream);
  chamfer_sym<<<dim3(SM, SN, B_), THREADS, 0, stream>>>(
      pred, gt, rowmin, colmin, accws);
  chamfer_fin<<<64, 256, 0, stream>>>(rowmin, accws, out);
}

// Round 8
// 100.684 us; speedup vs baseline: 1.0413x; 1.0082x over previous
//
#include <hip/hip_runtime.h>

// Chamfer distance: B=4, N=M=8192, D=3, fp32. VALU issue-bound.
// Two-direction brute force in the R4 structure (proven 100% VALU issue),
// with issues/pair cut 7.0 -> ~3.7: QPT=8 queries/thread amortizes each
// broadcast ds_read_b128; forced v_min3_f32; S=32 splits for occupancy.

#define B_ 4
#define N_ 8192
#define QPT 8          // queries per thread
#define THREADS 256
#define S_ 32          // target splits
#define TT (N_ / S_)   // 256 targets staged per block

__device__ __forceinline__ float min3f(float a, float b, float c) {
  float d;
  asm("v_min3_f32 %0, %1, %2, %3" : "=v"(d) : "v"(a), "v"(b), "v"(c));
  return d;
}

// grid: (N_/(THREADS*QPT)=4, S_=32, 2*B_=8)
__global__ __launch_bounds__(THREADS) void chamfer_min2(
    const float* __restrict__ pred, const float* __restrict__ gt,
    float* __restrict__ partial, float* __restrict__ accws) {
  __shared__ float4 sh[TT];     // 4 KB: packed (x,y,z,|t|^2)

  const int tid = threadIdx.x;
  const int dirb = blockIdx.z;          // 0..7
  const int dir = dirb >> 2;            // 0: pred->gt, 1: gt->pred
  const int b = dirb & 3;

  if (blockIdx.x == 0 && blockIdx.y == 0 && blockIdx.z == 0 && tid < 2)
    ((unsigned*)accws)[tid] = 0u;       // zero sum+counter for fin

  const float* qsrc = (dir == 0 ? pred : gt) + (size_t)b * N_ * 3;
  const float* tsrc = (dir == 0 ? gt : pred) + (size_t)b * N_ * 3;

  // ---- stage TT targets: one point per thread (TT == THREADS) ----
  {
    const float* tb = tsrc + (size_t)blockIdx.y * TT * 3;
    const float x = tb[3 * tid], y = tb[3 * tid + 1], z = tb[3 * tid + 2];
    sh[tid] = make_float4(x, y, z, fmaf(x, x, fmaf(y, y, z * z)));
  }
  __syncthreads();

  // ---- 8 queries per thread ----
  const int qbase = blockIdx.x * (THREADS * QPT) + tid;
  float nx[QPT], ny[QPT], nz[QPT], q2[QPT], acc[QPT];
#pragma unroll
  for (int k = 0; k < QPT; ++k) {
    const int qi = qbase + k * THREADS;
    const float x = qsrc[3 * qi], y = qsrc[3 * qi + 1], z = qsrc[3 * qi + 2];
    nx[k] = -2.0f * x; ny[k] = -2.0f * y; nz[k] = -2.0f * z;
    q2[k] = fmaf(x, x, fmaf(y, y, z * z));
    acc[k] = 3.4e38f;
  }

  // ---- main loop: 16 targets per outer iter, broadcast LDS reads ----
  for (int j0 = 0; j0 < TT; j0 += 16) {
#pragma unroll
    for (int jj = 0; jj < 16; jj += 2) {
      const float4 t0 = sh[j0 + jj];
      const float4 t1 = sh[j0 + jj + 1];
#pragma unroll
      for (int k = 0; k < QPT; ++k) {
        const float s0 = fmaf(nx[k], t0.x, fmaf(ny[k], t0.y, fmaf(nz[k], t0.z, t0.w)));
        const float s1 = fmaf(nx[k], t1.x, fmaf(ny[k], t1.y, fmaf(nz[k], t1.z, t1.w)));
        acc[k] = min3f(acc[k], s0, s1);
      }
    }
  }

  // ---- store split partials (coalesced) ----
  float* dst = partial + ((size_t)dirb * S_ + blockIdx.y) * N_;
#pragma unroll
  for (int k = 0; k < QPT; ++k) {
    const int qi = qbase + k * THREADS;
    dst[qi] = fmaxf(q2[k] + acc[k], 0.0f);
  }
}

// fin: 16384 threads, 4 queries each (float4 over qi), min over S_=32 splits.
__global__ __launch_bounds__(256) void chamfer_fin(
    const float* __restrict__ partial, float* __restrict__ accws,
    float* __restrict__ out) {
  const int t = blockIdx.x * 256 + threadIdx.x;   // 0..16383
  const int base = t * 4;                         // query group
  const int dirb = base >> 13;
  const int qi = base & (N_ - 1);

  const float4* p = (const float4*)(partial + (size_t)dirb * S_ * N_ + qi);
  const int stride4 = N_ / 4;                     // float4 stride between splits
  float4 m = p[0];
#pragma unroll
  for (int s = 1; s < S_; s += 2) {
    const float4 a = p[(size_t)s * stride4];
    const float4 c = p[(size_t)(s + 1 < S_ ? s + 1 : s) * stride4];
    m.x = min3f(m.x, a.x, c.x);
    m.y = min3f(m.y, a.y, c.y);
    m.z = min3f(m.z, a.z, c.z);
    m.w = min3f(m.w, a.w, c.w);
  }
  float sum = sqrtf(m.x) + sqrtf(m.y) + sqrtf(m.z) + sqrtf(m.w);

#pragma unroll
  for (int off = 32; off > 0; off >>= 1) sum += __shfl_down(sum, off, 64);
  __shared__ float ws4[4];
  const int lane = threadIdx.x & 63, wid = threadIdx.x >> 6;
  if (lane == 0) ws4[wid] = sum;
  __syncthreads();
  if (threadIdx.x == 0) {
    const float bs = (ws4[0] + ws4[1]) + (ws4[2] + ws4[3]);
    atomicAdd(&accws[0], bs);
    __threadfence();
    const unsigned old = atomicAdd(((unsigned*)accws) + 1, 1u);
    if (old == gridDim.x - 1) {
      __threadfence();
      const float tot = atomicAdd(&accws[0], 0.0f);
      out[0] = tot * (1.0f / 32768.0f);   // /(B*N) per direction, N==M
    }
  }
}

extern "C" void kernel_launch(void* const* d_in, const int* in_sizes, int n_in,
                              void* d_out, int out_size, void* d_ws, size_t ws_size,
                              hipStream_t stream) {
  const float* pred = (const float*)d_in[0];  // [B, N, 3]
  const float* gt   = (const float*)d_in[1];  // [B, M, 3]
  float* out = (float*)d_out;

  float* accws = (float*)d_ws;                          // 2 words
  float* partial = (float*)((char*)d_ws + 64);          // 8*S_*N_ floats = 8 MB

  chamfer_min2<<<dim3(N_ / (THREADS * QPT), S_, 2 * B_), THREADS, 0, stream>>>(
      pred, gt, partial, accws);
  chamfer_fin<<<64, 256, 0, stream>>>(partial, accws, out);
}

// Round 9
// 87.599 us; speedup vs baseline: 1.1968x; 1.1494x over previous
//
#include <hip/hip_runtime.h>

// Chamfer distance: B=4, N=M=8192, D=3, fp32 -> scalar.
// MFMA formulation: d2 = |q|^2 + |t|^2 - 2 q.t packed into K=16 of
// mfma_f32_32x32x16_bf16 via bf16 hi/lo splitting (13 slots):
//   k0..2 : A=-2qh_xyz        B=th_xyz
//   k3..5 : A=-2qh_xyz        B=tl_xyz
//   k6..8 : A=-2ql_xyz        B=th_xyz
//   k9,10 : A=q2h,q2l         B=1,1
//   k11,12: A=1,1             B=t2h,t2l
// One MFMA = 1024 d2 values; VALU only does 16 v_min per tile.
// Two passes (dir in grid.y): row-min only, block-owned rows, plain stores.

#define B_ 4
#define N_ 8192
#define THREADS 512

typedef float f32x16 __attribute__((ext_vector_type(16)));
typedef short short8 __attribute__((ext_vector_type(8)));
typedef unsigned short ushort8 __attribute__((ext_vector_type(8)));

__device__ __forceinline__ unsigned short f2bf(float x) {
  unsigned u = __float_as_uint(x);
  u = u + 0x7FFFu + ((u >> 16) & 1u);          // RNE
  return (unsigned short)(u >> 16);
}
__device__ __forceinline__ float bf2f(unsigned short h) {
  return __uint_as_float(((unsigned)h) << 16);
}

// Pack A-form (queries/rows) and B-form (targets/cols) for both directions.
// Apack slots: [0..32768) = pred (dir0 rows), [32768..) = gt (dir1 rows).
// Bpack slots: [0..32768) = gt   (dir0 cols), [32768..) = pred (dir1 cols).
__global__ __launch_bounds__(256) void chamfer_pack(
    const float* __restrict__ pred, const float* __restrict__ gt,
    unsigned short* __restrict__ Apack, unsigned short* __restrict__ Bpack,
    float* __restrict__ accws) {
  const int i = blockIdx.x * 256 + threadIdx.x;   // 0..65535
  if (i < 2) ((unsigned*)accws)[i] = 0u;          // zero sum + counter
  const int half = B_ * N_;
  const float* src = (i < half) ? pred : gt;
  const int k = (i < half) ? i : i - half;
  const float x = src[3 * k], y = src[3 * k + 1], z = src[3 * k + 2];
  const float q2 = fmaf(x, x, fmaf(y, y, z * z));

  const float ux = -2.f * x, uy = -2.f * y, uz = -2.f * z;
  const unsigned short uhx = f2bf(ux), uhy = f2bf(uy), uhz = f2bf(uz);
  const unsigned short ulx = f2bf(ux - bf2f(uhx));
  const unsigned short uly = f2bf(uy - bf2f(uhy));
  const unsigned short ulz = f2bf(uz - bf2f(uhz));
  const unsigned short thx = f2bf(x), thy = f2bf(y), thz = f2bf(z);
  const unsigned short tlx = f2bf(x - bf2f(thx));
  const unsigned short tly = f2bf(y - bf2f(thy));
  const unsigned short tlz = f2bf(z - bf2f(thz));
  const unsigned short q2h = f2bf(q2);
  const unsigned short q2l = f2bf(q2 - bf2f(q2h));
  const unsigned short one = 0x3F80u;

  const size_t aslot = (size_t)i;
  const size_t bslot = (size_t)((i < half) ? i + half : i - half);

  ushort8 alo = {uhx, uhy, uhz, uhx, uhy, uhz, ulx, uly};
  ushort8 ahi = {ulz, q2h, q2l, one, one, 0, 0, 0};
  ushort8 blo = {thx, thy, thz, tlx, tly, tlz, thx, thy};
  ushort8 bhi = {thz, one, one, q2h, q2l, 0, 0, 0};
  *(ushort8*)(Apack + aslot * 16) = alo;
  *(ushort8*)(Apack + aslot * 16 + 8) = ahi;
  *(ushort8*)(Bpack + bslot * 16) = blo;
  *(ushort8*)(Bpack + bslot * 16 + 8) = bhi;
}

// grid (128 panels, 8 dirb). 8 waves = 2 row-subtiles x 4 col-slices.
// Block owns 64 rows; sweeps all 8192 cols in 64 steps (128 cols/step).
__global__ __launch_bounds__(THREADS, 4) void chamfer_mfma(
    const unsigned short* __restrict__ Apack,
    const unsigned short* __restrict__ Bpack,
    float* __restrict__ rowmin) {
  __shared__ unsigned rowlds[64];
  const int tid = threadIdx.x;
  const int dirb = blockIdx.y;            // dir*4 + b
  const int panel = blockIdx.x;           // 64-row panel
  const int w = tid >> 6, l = tid & 63;
  const int wr = w >> 2, wc = w & 3;
  const int l31 = l & 31, lhi = l >> 5;

  if (tid < 64) rowlds[tid] = 0x7F7FFFFFu;
  __syncthreads();

  // A fragment (fixed per wave): row = panel*64 + wr*32 + (l&31), k-half by lhi.
  const int row = panel * 64 + wr * 32 + l31;
  const short8 afrag =
      *(const short8*)(Apack + ((size_t)dirb * N_ + row) * 16 + lhi * 8);

  // B fragment base: col = wc*32 + (l&31); advances 128 cols (4 KB) per step.
  const unsigned short* bp =
      Bpack + ((size_t)dirb * N_ + wc * 32 + l31) * 16 + lhi * 8;

  const f32x16 zacc = {};     // zero C: each MFMA output is a fresh d2 tile
  float racc[16];
#pragma unroll
  for (int r = 0; r < 16; ++r) racc[r] = 3.4e38f;

#pragma unroll 2
  for (int step = 0; step < 64; ++step) {
    const short8 bfrag = *(const short8*)(bp + (size_t)step * 128 * 16);
    const f32x16 d =
        __builtin_amdgcn_mfma_f32_32x32x16_bf16(afrag, bfrag, zacc, 0, 0, 0);
#pragma unroll
    for (int r = 0; r < 16; ++r) racc[r] = fminf(racc[r], d[r]);
  }

  // clamp (split rounding can give tiny negatives), butterfly over 32 col-lanes
#pragma unroll
  for (int r = 0; r < 16; ++r) racc[r] = fmaxf(racc[r], 0.0f);
#pragma unroll
  for (int m = 1; m <= 16; m <<= 1)
#pragma unroll
    for (int r = 0; r < 16; ++r)
      racc[r] = fminf(racc[r], __shfl_xor(racc[r], m, 64));

  // lanes 0 and 32 hold the 16-row mins for their half; combine across 4 wc-waves
  if (l31 == 0) {
#pragma unroll
    for (int r = 0; r < 16; ++r) {
      const int lr = wr * 32 + (r & 3) + 8 * (r >> 2) + 4 * lhi;
      atomicMin(&rowlds[lr], __float_as_uint(racc[r]));
    }
  }
  __syncthreads();
  if (tid < 64)
    rowmin[(size_t)dirb * N_ + panel * 64 + tid] = __uint_as_float(rowlds[tid]);
}

// 65536 d2 mins -> sqrt -> sum -> scaled scalar (counter-trick final write).
__global__ __launch_bounds__(256) void chamfer_fin(
    const float* __restrict__ rowmin, float* __restrict__ accws,
    float* __restrict__ out) {
  const int t = blockIdx.x * 256 + threadIdx.x;   // 0..16383
  const float4 v = ((const float4*)rowmin)[t];
  float sum = sqrtf(fmaxf(v.x, 0.f)) + sqrtf(fmaxf(v.y, 0.f)) +
              sqrtf(fmaxf(v.z, 0.f)) + sqrtf(fmaxf(v.w, 0.f));
#pragma unroll
  for (int off = 32; off > 0; off >>= 1) sum += __shfl_down(sum, off, 64);
  __shared__ float ws4[4];
  const int lane = threadIdx.x & 63, wid = threadIdx.x >> 6;
  if (lane == 0) ws4[wid] = sum;
  __syncthreads();
  if (threadIdx.x == 0) {
    const float bs = (ws4[0] + ws4[1]) + (ws4[2] + ws4[3]);
    atomicAdd(&accws[0], bs);
    __threadfence();
    const unsigned old = atomicAdd(((unsigned*)accws) + 1, 1u);
    if (old == gridDim.x - 1) {
      __threadfence();
      const float tot = atomicAdd(&accws[0], 0.0f);
      out[0] = tot * (1.0f / 32768.0f);   // /(B*N) per direction, N==M
    }
  }
}

extern "C" void kernel_launch(void* const* d_in, const int* in_sizes, int n_in,
                              void* d_out, int out_size, void* d_ws, size_t ws_size,
                              hipStream_t stream) {
  const float* pred = (const float*)d_in[0];  // [B, N, 3]
  const float* gt   = (const float*)d_in[1];  // [B, M, 3]
  float* out = (float*)d_out;

  float* accws = (float*)d_ws;                                   // 2 words
  unsigned short* Apack = (unsigned short*)((char*)d_ws + 64);   // 2 MB
  unsigned short* Bpack = Apack + (size_t)2 * B_ * N_ * 16;      // 2 MB
  float* rowmin = (float*)(Bpack + (size_t)2 * B_ * N_ * 16);    // 256 KB

  chamfer_pack<<<256, 256, 0, stream>>>(pred, gt, Apack, Bpack, accws);
  chamfer_mfma<<<dim3(128, 8), THREADS, 0, stream>>>(Apack, Bpack, rowmin);
  chamfer_fin<<<64, 256, 0, stream>>>(rowmin, accws, out);
}